// Round 10
// baseline (2173.889 us; speedup 1.0000x reference)
//
#include <hip/hip_runtime.h>

#define PI_F 3.14159265358979323846f

template<int v> struct ic_t { static constexpr int value = v; };

template<int N, int I = 0, typename F>
__device__ __forceinline__ void sfor(F&& f) {
  if constexpr (I < N) { f(ic_t<I>{}); sfor<N, I + 1>(static_cast<F&&>(f)); }
}

__host__ __device__ constexpr int fold_idx(int t) {
  t &= 63;
  return (t <= 16) ? t : (t <= 32) ? (32 - t) : (t <= 48) ? (t - 32) : (64 - t);
}
__host__ __device__ constexpr float fold_sgn(int t) {
  t &= 63;
  return (t <= 16) ? 1.f : (t <= 48) ? -1.f : 1.f;
}

// cos(k*pi/32), k=0..16, f32-rounded literals (compile-time only -> 0 VGPRs).
__device__ constexpr float CCV[17] = {
  1.0f, 0.9951847266721969f, 0.9807852804032304f, 0.9569403357322088f,
  0.9238795325112867f, 0.8819212643483550f, 0.8314696123025452f,
  0.7730104533627370f, 0.7071067811865476f, 0.6343932841636455f,
  0.5555702330196022f, 0.4713967368259976f, 0.3826834323650898f,
  0.2902846772544623f, 0.1950903220161283f, 0.0980171403295606f, 0.0f};

// cos/sin(2*pi*T/64); T must be compile-time -> folds to a literal constant.
#define TCOS(T) (fold_sgn(T) * CCV[fold_idx(T)])
#define TSIN(T) (fold_sgn(((T) + 48) & 63) * CCV[fold_idx(((T) + 48) & 63)])

typedef __attribute__((address_space(1))) const unsigned int gu32_t;
typedef __attribute__((address_space(3))) unsigned int lu32_t;

// ---------------------------------------------------------------------------
// Kernel 1 (REDESIGNED): forward low-mode DFT via LDS-staged slabs.
// grid 2048 = {q,k} x channel, block 512 (8 waves).
// r6-r9 lesson: direct-load structure demands ~80 VGPR -> either 2 waves/SIMD
// (191us) or spills under a 64-cap. This design's demand is ~55 BY STRUCTURE:
//  - global_load_lds stages slab x[n0][.][.] (8 KB contiguous): 0 load regs.
//  - DFT order n1 (from LDS) -> n0 (literal twiddles + radix-2 fold) -> n2.
//  - thread (k1, n2-pair) holds B[k0<8] = 32 regs; n1 range split across wave
//    halves (combine once at end); n1-twiddle = in-register rotation.
// LDS 33 KB: slabs dbuf [slot<2][ab<2][2048f] = 32 KB, aliased by final
// Bt[64][64] swizzled tile. One barrier per n0-pair iteration.
// ---------------------------------------------------------------------------
__global__ __launch_bounds__(512, 4)
void k1_fwd_dft(const float* __restrict__ qg, const float* __restrict__ kg,
                float2* __restrict__ qsel, float2* __restrict__ ksel)
{
  __shared__ float2 SHB[4096];   // 32 KB (aliased: slabs then Bt)
  __shared__ float2 tw64[64];

  float* const slabs = (float*)SHB;
  float2* const Bt = SHB;

  const int tid = threadIdx.x;
  const int lane = tid & 63;
  const int wv = tid >> 6;                       // 0..7
  const int bid = blockIdx.x;
  const int ch = bid & 1023;
  const float* __restrict__ src = (bid < 1024 ? qg : kg) + (size_t)ch * 65536;
  float2* __restrict__ dst = (bid < 1024 ? qsel : ksel) + ch * 512;

  if (tid < 64) {
    float s, c;
    sincosf((float)tid * (2.f * PI_F / 64.f), &s, &c);
    tw64[tid] = make_float2(c, s);
  }

  const int h  = wv >> 2;                        // n1 half: 0 -> 0..15, 1 -> 16..31
  const int k1 = ((wv & 3) << 1) | (lane >> 5);  // 0..7 (per-lane)
  const int p  = lane & 31;                      // n2 pair: n2 = 2p, 2p+1

  // n1-twiddle rotation step e^{+2pi i k1/32}; exact seed per slab = (+-1, 0).
  float stp_s, stp_c;
  sincosf((float)k1 * (2.f * PI_F / 32.f), &stp_s, &stp_c);

  // B accumulators: [k0<8] x {n2=2p, 2p+1}, complex.
  float Br0[8], Bi0[8], Br1[8], Bi1[8];
  sfor<8>([&](auto K) { constexpr int k = decltype(K)::value;
    Br0[k] = 0.f; Bi0[k] = 0.f; Br1[k] = 0.f; Bi1[k] = 0.f; });

  const int stoff = (wv << 8) + (lane << 2);     // per-lane stage src offset (floats)

  // stage slab pair (n0 = pr, n0 = pr+16) into slot: 2 calls, 16 KB total.
  auto STAGE = [&](int slotc, int prc) {
    __builtin_amdgcn_global_load_lds(
        (gu32_t*)(const void*)(src + prc * 2048 + stoff),
        (lu32_t*)(void*)(slabs + slotc * 4096 + (wv << 8)), 16, 0, 0);
    __builtin_amdgcn_global_load_lds(
        (gu32_t*)(const void*)(src + (prc + 16) * 2048 + stoff),
        (lu32_t*)(void*)(slabs + slotc * 4096 + 2048 + (wv << 8)), 16, 0, 0);
  };

  const int cbase = h * 1024 + 2 * p;            // slab-read base (floats)
  const float seed = ((k1 & h) & 1) ? -1.f : 1.f;

  STAGE(0, 0);
  sfor<16>([&](auto PR) {
    constexpr int pr = decltype(PR)::value;
    constexpr int slot = pr & 1;
    __syncthreads();                 // vmcnt(0) drained -> slot's slabs ready;
                                     // prev readers of slot^1 are done
    if constexpr (pr < 15) STAGE(slot ^ 1, pr + 1);

    // X1 over this thread's n1 half, for slab A (n0=pr) and B (n0=pr+16)
    const float* __restrict__ sa = slabs + slot * 4096 + cbase;
    float war = seed, wai = 0.f;
    float xar0 = 0.f, xai0 = 0.f, xar1 = 0.f, xai1 = 0.f;
    float xbr0 = 0.f, xbi0 = 0.f, xbr1 = 0.f, xbi1 = 0.f;
    sfor<16>([&](auto JC) {
      constexpr int j = decltype(JC)::value;
      const float2 va = *(const float2*)(sa + j * 64);          // ds_read_b64
      const float2 vb = *(const float2*)(sa + 2048 + j * 64);
      xar0 = fmaf(va.x, war, xar0); xai0 = fmaf(-va.x, wai, xai0);
      xar1 = fmaf(va.y, war, xar1); xai1 = fmaf(-va.y, wai, xai1);
      xbr0 = fmaf(vb.x, war, xbr0); xbi0 = fmaf(-vb.x, wai, xbi0);
      xbr1 = fmaf(vb.y, war, xbr1); xbi1 = fmaf(-vb.y, wai, xbi1);
      if constexpr (j < 15) {
        const float nwr = fmaf(war, stp_c, -(wai * stp_s));
        const float nwi = fmaf(wai, stp_c,  (war * stp_s));
        war = nwr; wai = nwi;
      }
    });
    // radix-2 fold over n0-pair: w^(k0(pr+16)) = (-1)^k0 w^(k0 pr)
    const float sr0 = xar0 + xbr0, si0 = xai0 + xbi0;
    const float dr0 = xar0 - xbr0, di0 = xai0 - xbi0;
    const float sr1 = xar1 + xbr1, si1 = xai1 + xbi1;
    const float dr1 = xar1 - xbr1, di1 = xai1 - xbi1;
    sfor<8>([&](auto KC) {
      constexpr int k0 = decltype(KC)::value;
      constexpr int t = (2 * k0 * pr) & 63;       // literal twiddle
      const float gr0 = (k0 & 1) ? dr0 : sr0, gi0 = (k0 & 1) ? di0 : si0;
      const float gr1 = (k0 & 1) ? dr1 : sr1, gi1 = (k0 & 1) ? di1 : si1;
      Br0[k0] = fmaf(gr0, TCOS(t), fmaf( gi0, TSIN(t), Br0[k0]));
      Bi0[k0] = fmaf(gi0, TCOS(t), fmaf(-gr0, TSIN(t), Bi0[k0]));
      Br1[k0] = fmaf(gr1, TCOS(t), fmaf( gi1, TSIN(t), Br1[k0]));
      Bi1[k0] = fmaf(gi1, TCOS(t), fmaf(-gr1, TSIN(t), Bi1[k0]));
    });
  });

  // ---- combine halves into swizzled Bt (aliases slabs; all reads done)
  __syncthreads();
  if (h) {
    sfor<8>([&](auto KC) {
      constexpr int k0 = decltype(KC)::value;
      const int row = k1 * 8 + k0;
      Bt[row * 64 + ((2 * p     + row) & 63)] = make_float2(Br0[k0], Bi0[k0]);
      Bt[row * 64 + ((2 * p + 1 + row) & 63)] = make_float2(Br1[k0], Bi1[k0]);
    });
  }
  __syncthreads();
  if (!h) {
    sfor<8>([&](auto KC) {
      constexpr int k0 = decltype(KC)::value;
      const int row = k1 * 8 + k0;
      const int c0 = row * 64 + ((2 * p     + row) & 63);
      const int c1 = row * 64 + ((2 * p + 1 + row) & 63);
      const float2 o0 = Bt[c0], o1 = Bt[c1];
      Bt[c0] = make_float2(o0.x + Br0[k0], o0.y + Bi0[k0]);
      Bt[c1] = make_float2(o1.x + Br1[k0], o1.y + Bi1[k0]);
    });
  }
  __syncthreads();

  // ---- phase 3: thread (wv,lane): k2 = wv, row = lane (= k1*8+k0)
  {
    float oR = 0.f, oI = 0.f;
    #pragma unroll 8
    for (int n2 = 0; n2 < 64; ++n2) {
      const float2 b = Bt[lane * 64 + ((n2 + lane) & 63)];  // 2-way banks
      const float2 w = tw64[(wv * n2) & 63];                // wave-uniform
      oR = fmaf(b.x, w.x, fmaf( b.y, w.y, oR));
      oI = fmaf(b.y, w.x, fmaf(-b.x, w.y, oI));
    }
    dst[((lane & 7) << 6) + ((lane >> 3) << 3) + wv] =
        make_float2(oR * (1.f / 256.f), oI * (1.f / 256.f));
  }
}

// ---------------------------------------------------------------------------
// Kernel 2: fused complex attention  xqkv[e,x] = sum_y tanh(sum_e' Q K) * K.
// grid 512 = (b*H+h)*8 + xo; block 512 = 64 x-rows * 8 y-groups (64 y each).
// ---------------------------------------------------------------------------
__global__ __launch_bounds__(512, 4)
void k2_attn(const float2* __restrict__ qsel, const float2* __restrict__ ksel,
             float2* __restrict__ xqkv)
{
  __shared__ float2 Kl[8192];   // [e<16][y<512], reused as reduction buffer
  const int tid = threadIdx.x;
  const int bh = blockIdx.x >> 3;
  const int xo = blockIdx.x & 7;

  const float2* __restrict__ kb = ksel + bh * 8192;
  for (int i = tid; i < 8192; i += 512) Kl[i] = kb[i];

  const int xr = tid & 63;
  const int yh = tid >> 6;           // 0..7
  const int x = xo * 64 + xr;
  const float2* __restrict__ qb = qsel + bh * 8192;
  float qr[16], qi[16], ar[16], ai[16];
  sfor<16>([&](auto E) {
    constexpr int e = decltype(E)::value;
    const float2 v = qb[e * 512 + x];
    qr[e] = v.x; qi[e] = v.y;
    ar[e] = 0.f; ai[e] = 0.f;
  });
  __syncthreads();

  const int y0 = yh * 64;
  for (int y = y0; y < y0 + 64; ++y) {
    float kr[16], ki[16];
    float sr = 0.f, si = 0.f;
    sfor<16>([&](auto E) {
      constexpr int e = decltype(E)::value;
      const float2 v = Kl[e * 512 + y];      // wave-uniform -> broadcast
      kr[e] = v.x; ki[e] = v.y;
      sr = fmaf(qr[e], v.x, fmaf(-qi[e], v.y, sr));
      si = fmaf(qr[e], v.y, fmaf( qi[e], v.x, si));
    });
    // complex tanh(sr + i si) = (sinh 2a + i sin 2b) / (cosh 2a + cos 2b)
    float a2 = 2.f * sr;
    a2 = fminf(fmaxf(a2, -30.f), 30.f);
    const float b2 = 2.f * si;
    const float ea = expf(a2);
    const float ei = 1.f / ea;
    const float sh = 0.5f * (ea - ei);
    const float chp = 0.5f * (ea + ei);
    float sb, cb;
    sincosf(b2, &sb, &cb);
    const float inv = 1.f / (chp + cb);
    const float tr = sh * inv;
    const float ti = sb * inv;
    sfor<16>([&](auto E) {
      constexpr int e = decltype(E)::value;
      ar[e] = fmaf(tr, kr[e], fmaf(-ti, ki[e], ar[e]));
      ai[e] = fmaf(tr, ki[e], fmaf( ti, kr[e], ai[e]));
    });
  }
  __syncthreads();
  float* __restrict__ red = (float*)Kl;   // K dead; 16384 floats available
  if (yh) {
    const int g = yh - 1;                 // 0..6
    sfor<16>([&](auto E) {
      constexpr int e = decltype(E)::value;
      red[(g * 32 + 2 * e) * 64 + xr] = ar[e];
      red[(g * 32 + 2 * e + 1) * 64 + xr] = ai[e];
    });
  }
  __syncthreads();
  if (!yh) {
    float2* __restrict__ ob = xqkv + bh * 8192;
    sfor<16>([&](auto E) {
      constexpr int e = decltype(E)::value;
      float sr2 = ar[e], si2 = ai[e];
      #pragma unroll
      for (int g = 0; g < 7; ++g) {
        sr2 += red[(g * 32 + 2 * e) * 64 + xr];
        si2 += red[(g * 32 + 2 * e + 1) * 64 + xr];
      }
      ob[e * 512 + x] = make_float2(sr2, si2);
    });
  }
}

// ---------------------------------------------------------------------------
// Kernel 3: w-multiply + analytic canonicalized inverse transform.
// out = (1/2^22) * sum_{k} w2(k2) cos(2pi k2 n2/64) * Re[F e^{i 2pi(k0n0+k1n1)/32}]
// grid 1024 = (b,h,o); block 256. Separable: A over k2, B over k1, C over k0.
// ---------------------------------------------------------------------------
#define SCALE_OUT (1.f / 4194304.f)

__global__ __launch_bounds__(256, 2)
void k3_inv(const float2* __restrict__ xqkv, const float* __restrict__ w_re,
            const float* __restrict__ w_im, float* __restrict__ out)
{
  __shared__ float2 Fs[512];
  __shared__ float cn[64];                   // cos(2*pi*t/64)
  __shared__ float Ur[4096], Ui[4096];       // [p=k0*8+k1][n2]
  __shared__ float Vr[2048], Vi[2048];       // [k0*4+n1loc][n2], 4-n1 chunks

  const int tid = threadIdx.x;
  const int bho = blockIdx.x;
  const int o = bho & 15;
  const int h = (bho >> 4) & 7;
  const int bh = bho >> 4;                   // b*8+h

  if (tid < 64) cn[tid] = cosf((float)tid * (PI_F / 32.f));

  float cc[17];
  sfor<17>([&](auto J) { constexpr int j = decltype(J)::value;
    cc[j] = cosf((float)j * (PI_F / 32.f)); });
  #define TCOSr(T) (fold_sgn(T) * cc[fold_idx(T)])
  #define TSINr(T) (fold_sgn(((T) + 48) & 63) * cc[fold_idx(((T) + 48) & 63)])

  // F[x] = sum_e xqkv[e,x] * w[e,o,x], scaled
  const float2* __restrict__ xb = xqkv + bh * 8192;
  const float* __restrict__ wrb = w_re + ((size_t)(h * 256 + o)) * 512;
  const float* __restrict__ wib = w_im + ((size_t)(h * 256 + o)) * 512;
  for (int x = tid; x < 512; x += 256) {
    float fr = 0.f, fi = 0.f;
    sfor<16>([&](auto E) {
      constexpr int e = decltype(E)::value;
      const float2 v = xb[e * 512 + x];
      const float wr = wrb[e * 8192 + x];
      const float wi = wib[e * 8192 + x];
      fr = fmaf(v.x, wr, fmaf(-v.y, wi, fr));
      fi = fmaf(v.x, wi, fmaf( v.y, wr, fi));
    });
    Fs[x] = make_float2(fr * SCALE_OUT, fi * SCALE_OUT);
  }
  __syncthreads();

  const int n2 = tid & 63;
  const int wv = tid >> 6;

  // stage A: U[p][n2] = sum_k2 w2(k2) cos(2pi k2 n2/64) F[p*8+k2]
  #pragma unroll
  for (int i = 0; i < 16; ++i) {
    const int p = wv * 16 + i;
    float ur = 0.f, ui = 0.f;
    sfor<8>([&](auto KC) {
      constexpr int k2 = decltype(KC)::value;
      const float2 f = Fs[p * 8 + k2];       // wave-uniform broadcast
      const float cv = cn[(k2 * n2) & 63];
      const float wgt = (k2 == 0) ? cv : 2.f * cv;
      ur = fmaf(wgt, f.x, ur);
      ui = fmaf(wgt, f.y, ui);
    });
    Ur[p * 64 + n2] = ur;
    Ui[p * 64 + n2] = ui;
  }
  __syncthreads();

  // per-thread U registers for its two k0 columns
  float u_r[2][8], u_i[2][8];
  sfor<2>([&](auto JC) {
    constexpr int j = decltype(JC)::value;
    sfor<8>([&](auto KC) {
      constexpr int k1 = decltype(KC)::value;
      const int p = (wv * 2 + j) * 8 + k1;
      u_r[j][k1] = Ur[p * 64 + n2];
      u_i[j][k1] = Ui[p * 64 + n2];
    });
  });

  float* __restrict__ ob = out + (size_t)bho * 65536;

  for (int chq = 0; chq < 8; ++chq) {        // 4 n1 values per chunk
    // stage B: V[k0][n1loc][n2] = sum_k1 U * e^{+i 2pi k1 n1/32}
    sfor<2>([&](auto JC) {
      constexpr int j = decltype(JC)::value;
      const int k0 = wv * 2 + j;
      sfor<4>([&](auto LC) {
        constexpr int l = decltype(LC)::value;
        const int n1 = chq * 4 + l;
        float vr = 0.f, vi = 0.f;
        sfor<8>([&](auto KC) {
          constexpr int k1 = decltype(KC)::value;
          const int t = (2 * k1 * n1) & 63;  // wave-uniform -> broadcast reads
          const float cv = cn[t];
          const float sv = cn[(t + 48) & 63];
          vr = fmaf(u_r[j][k1], cv, fmaf(-u_i[j][k1], sv, vr));
          vi = fmaf(u_r[j][k1], sv, fmaf( u_i[j][k1], cv, vi));
        });
        Vr[(k0 * 4 + l) * 64 + n2] = vr;
        Vi[(k0 * 4 + l) * 64 + n2] = vi;
      });
    });
    __syncthreads();
    // stage C: out[n0][n1][n2] = sum_k0 Vr cos - Vi sin   (literal twiddles)
    {
      const int l = wv;
      float vrr[8], vii[8];
      sfor<8>([&](auto KC) {
        constexpr int k0 = decltype(KC)::value;
        vrr[k0] = Vr[(k0 * 4 + l) * 64 + n2];
        vii[k0] = Vi[(k0 * 4 + l) * 64 + n2];
      });
      const int n1 = chq * 4 + l;
      float* __restrict__ op = ob + n1 * 64 + n2;
      sfor<32>([&](auto NC) {
        constexpr int n0 = decltype(NC)::value;
        float acc = vrr[0];
        sfor<7>([&](auto KC) {
          constexpr int k0 = decltype(KC)::value + 1;
          constexpr int t = (2 * k0 * n0) & 63;
          acc = fmaf(vrr[k0], TCOSr(t), fmaf(-vii[k0], TSINr(t), acc));
        });
        op[n0 * 2048] = acc;
      });
    }
    __syncthreads();
  }
}

// ---------------------------------------------------------------------------
extern "C" void kernel_launch(void* const* d_in, const int* in_sizes, int n_in,
                              void* d_out, int out_size, void* d_ws, size_t ws_size,
                              hipStream_t stream)
{
  (void)in_sizes; (void)n_in; (void)out_size; (void)ws_size;
  const float* q    = (const float*)d_in[0];
  const float* k    = (const float*)d_in[1];
  const float* w_re = (const float*)d_in[2];
  const float* w_im = (const float*)d_in[3];
  float* out = (float*)d_out;

  // workspace: qsel(4MB) | ksel(4MB) | xqkv(4MB), all [bh][e][x] float2
  float2* qsel = (float2*)d_ws;
  float2* ksel = qsel + 1024 * 512;
  float2* xqkv = ksel + 1024 * 512;

  hipLaunchKernelGGL(k1_fwd_dft, dim3(2048), dim3(512), 0, stream, q, k, qsel, ksel);
  hipLaunchKernelGGL(k2_attn,    dim3(512),  dim3(512), 0, stream, qsel, ksel, xqkv);
  hipLaunchKernelGGL(k3_inv,     dim3(1024), dim3(256), 0, stream, xqkv, w_re, w_im, out);
}

// Round 11
// 307.380 us; speedup vs baseline: 7.0723x; 7.0723x over previous
//
#include <hip/hip_runtime.h>

#define PI_F 3.14159265358979323846f

template<int v> struct ic_t { static constexpr int value = v; };

template<int N, int I = 0, typename F>
__device__ __forceinline__ void sfor(F&& f) {
  if constexpr (I < N) { f(ic_t<I>{}); sfor<N, I + 1>(static_cast<F&&>(f)); }
}

__host__ __device__ constexpr int fold_idx(int t) {
  t &= 63;
  return (t <= 16) ? t : (t <= 32) ? (32 - t) : (t <= 48) ? (t - 32) : (64 - t);
}
__host__ __device__ constexpr float fold_sgn(int t) {
  t &= 63;
  return (t <= 16) ? 1.f : (t <= 48) ? -1.f : 1.f;
}

// cos(k*pi/32), k=0..16, f32-rounded literals (compile-time only -> 0 VGPRs).
__device__ constexpr float CCV[17] = {
  1.0f, 0.9951847266721969f, 0.9807852804032304f, 0.9569403357322088f,
  0.9238795325112867f, 0.8819212643483550f, 0.8314696123025452f,
  0.7730104533627370f, 0.7071067811865476f, 0.6343932841636455f,
  0.5555702330196022f, 0.4713967368259976f, 0.3826834323650898f,
  0.2902846772544623f, 0.1950903220161283f, 0.0980171403295606f, 0.0f};

// cos/sin(2*pi*T/64); T must be compile-time -> folds to a literal constant.
#define TCOS(T) (fold_sgn(T) * CCV[fold_idx(T)])
#define TSIN(T) (fold_sgn(((T) + 48) & 63) * CCV[fold_idx(((T) + 48) & 63)])

// One radix-4 j-group of the 64-pt real row DFT (r1-verified math).
// j = 4G+m in 0..15; inputs x[j], x[j+16], x[j+32], x[j+48].
template<int G>
__device__ __forceinline__ void row_group(const float4& qa, const float4& qb,
                                          const float4& qc, const float4& qd,
                                          float* Xr, float* Xi)
{
  sfor<4>([&](auto MC) {
    constexpr int m = decltype(MC)::value;
    constexpr int j = 4 * G + m;
    const float xa = (m == 0) ? qa.x : (m == 1) ? qa.y : (m == 2) ? qa.z : qa.w;
    const float xb = (m == 0) ? qb.x : (m == 1) ? qb.y : (m == 2) ? qb.z : qb.w;
    const float xc = (m == 0) ? qc.x : (m == 1) ? qc.y : (m == 2) ? qc.z : qc.w;
    const float xd = (m == 0) ? qd.x : (m == 1) ? qd.y : (m == 2) ? qd.z : qd.w;
    const float s02 = xa + xc, d02 = xa - xc;
    const float s13 = xb + xd, d31 = xd - xb;
    const float g0 = s02 + s13, g2 = s02 - s13;
    Xr[0] += g0;                                   // k2=0 (imag identically 0)
    sfor<3>([&](auto EC) {                         // k2 = 2,4,6
      constexpr int k2 = 2 * (decltype(EC)::value + 1);
      constexpr int t = (k2 * j) & 63;
      const float g = (k2 == 4) ? g0 : g2;
      Xr[k2] = fmaf(g,  TCOS(t), Xr[k2]);
      Xi[k2] = fmaf(-g, TSIN(t), Xi[k2]);
    });
    sfor<4>([&](auto UC) {                         // k2 = 1,3,5,7
      constexpr int k2 = 2 * decltype(UC)::value + 1;
      constexpr int t = (k2 * j) & 63;
      const float gr = d02;
      const float gi = ((k2 & 3) == 1) ? d31 : -d31;
      Xr[k2] = fmaf(gr, TCOS(t), fmaf(gi,  TSIN(t), Xr[k2]));
      Xi[k2] = fmaf(gi, TCOS(t), fmaf(-gr, TSIN(t), Xi[k2]));
    });
  });
}

// ---------------------------------------------------------------------------
// Kernel 1 (REDESIGN r11): n2-first row DFT, ~55 live VGPR by structure.
// grid 2048 = {q,k} x channel, block 512 (8 waves), LDS 66.5 KB (2 blocks/CU).
// Stage 1 (2 passes of 512 rows): thread = row (n0,n1); 64-pt real DFT via
//   radix-4 fold, literal twiddles, 15 accumulators; loads = 16 float4 in an
//   A/B software pipeline (<=8 in flight), order pinned by sched_barrier(0).
//   Output Y[k2][row] complex to LDS (plane stride 1036 -> <=2-way banks).
// Stage 2+3 fused: thread (wave=n0 base, lane=(k1,k2)): z = sum_n1 Y*tw32,
//   folded into 8 k0-partials in regs; partials staged through the dead Y
//   region; thread tid writes final mode dst[tid] (coalesced).
// r10 lesson: global_load_lds variant spilled accumulators in-loop (4.8 GB
// scratch writes). This design has no persistent state across load loops.
// ---------------------------------------------------------------------------
__global__ __launch_bounds__(512, 4)
void k1_fwd_dft(const float* __restrict__ qg, const float* __restrict__ kg,
                float2* __restrict__ qsel, float2* __restrict__ ksel)
{
  __shared__ float2 Yb[8 * 1036];   // [k2][row<=1023], 66.3 KB; partials alias
  __shared__ float2 tw32[32];       // (cos,sin)(2*pi*t/32)

  const int tid = threadIdx.x;
  const int lane = tid & 63;
  const int wv = tid >> 6;                   // 0..7
  const int bid = blockIdx.x;
  const int ch = bid & 1023;
  const float* __restrict__ src = (bid < 1024 ? qg : kg) + (size_t)ch * 65536;
  float2* __restrict__ dst = (bid < 1024 ? qsel : ksel) + ch * 512;

  if (tid < 32) {
    float s, c;
    sincosf((float)tid * (2.f * PI_F / 32.f), &s, &c);
    tw32[tid] = make_float2(c, s);
  }

  // ---- stage 1: rows 0..1023 in two passes; Y[k2][row] <- row DFT
  #pragma unroll
  for (int p = 0; p < 2; ++p) {
    const int row = (p << 9) + tid;
    const float4* __restrict__ rq = (const float4*)(src + ((size_t)row << 6));
    float Xr[8], Xi[8];
    sfor<8>([&](auto K) { constexpr int k = decltype(K)::value;
      Xr[k] = 0.f; Xi[k] = 0.f; });

    // A/B pipelined loads: groups g use rq[g], rq[g+4], rq[g+8], rq[g+12]
    float4 A0 = rq[0], A1 = rq[4], A2 = rq[8],  A3 = rq[12];
    float4 B0 = rq[1], B1 = rq[5], B2 = rq[9],  B3 = rq[13];
    __builtin_amdgcn_sched_barrier(0);
    row_group<0>(A0, A1, A2, A3, Xr, Xi);
    __builtin_amdgcn_sched_barrier(0);
    A0 = rq[2]; A1 = rq[6]; A2 = rq[10]; A3 = rq[14];
    __builtin_amdgcn_sched_barrier(0);
    row_group<1>(B0, B1, B2, B3, Xr, Xi);
    __builtin_amdgcn_sched_barrier(0);
    B0 = rq[3]; B1 = rq[7]; B2 = rq[11]; B3 = rq[15];
    __builtin_amdgcn_sched_barrier(0);
    row_group<2>(A0, A1, A2, A3, Xr, Xi);
    __builtin_amdgcn_sched_barrier(0);
    row_group<3>(B0, B1, B2, B3, Xr, Xi);

    sfor<8>([&](auto KC) {
      constexpr int k2 = decltype(KC)::value;
      Yb[k2 * 1036 + row] = make_float2(Xr[k2], Xi[k2]);  // consecutive lanes
    });
  }
  __syncthreads();

  // ---- stage 2+3 fused: n1-DFT then k0-fold into register partials
  const int k1 = lane >> 3;
  const int k2 = lane & 7;
  float Wr[8], Wi[8];
  sfor<8>([&](auto K) { constexpr int k = decltype(K)::value;
    Wr[k] = 0.f; Wi[k] = 0.f; });

  sfor<4>([&](auto QC) {
    constexpr int q = decltype(QC)::value;
    const int n0 = wv + 8 * q;                  // wave-uniform
    const float2* __restrict__ yp = &Yb[k2 * 1036 + n0 * 32];
    float zr = 0.f, zi = 0.f;
    #pragma unroll
    for (int n1 = 0; n1 < 32; ++n1) {
      const float2 y = yp[n1];                  // 8-addr broadcast groups
      const float2 w = tw32[(k1 * n1) & 31];
      zr = fmaf(y.x, w.x, fmaf( y.y, w.y, zr));
      zi = fmaf(y.y, w.x, fmaf(-y.x, w.y, zi));
    }
    sfor<8>([&](auto KC) {
      constexpr int k0 = decltype(KC)::value;
      const float2 w = tw32[(k0 * n0) & 31];    // wave-uniform broadcast
      Wr[k0] = fmaf(zr, w.x, fmaf( zi, w.y, Wr[k0]));
      Wi[k0] = fmaf(zi, w.x, fmaf(-zr, w.y, Wi[k0]));
    });
  });
  __syncthreads();                              // all Y reads done

  // partials part[k0][wv][lane] into (dead) Y region: 32 KB
  float2* __restrict__ part = Yb;
  sfor<8>([&](auto KC) {
    constexpr int k0 = decltype(KC)::value;
    part[k0 * 512 + (wv << 6) + lane] = make_float2(Wr[k0], Wi[k0]);
  });
  __syncthreads();

  // reduce 8 wave-partials; thread tid owns mode (k0=wv, k1, k2) = tid
  {
    const float2* __restrict__ pp = &part[(wv << 9) + lane];
    float sr = 0.f, si = 0.f;
    #pragma unroll
    for (int w8 = 0; w8 < 8; ++w8) {
      const float2 v = pp[w8 * 64];
      sr += v.x; si += v.y;
    }
    dst[tid] = make_float2(sr * (1.f / 256.f), si * (1.f / 256.f));
  }
}

// ---------------------------------------------------------------------------
// Kernel 2: fused complex attention  xqkv[e,x] = sum_y tanh(sum_e' Q K) * K.
// grid 512 = (b*H+h)*8 + xo; block 512 = 64 x-rows * 8 y-groups (64 y each).
// ---------------------------------------------------------------------------
__global__ __launch_bounds__(512, 4)
void k2_attn(const float2* __restrict__ qsel, const float2* __restrict__ ksel,
             float2* __restrict__ xqkv)
{
  __shared__ float2 Kl[8192];   // [e<16][y<512], reused as reduction buffer
  const int tid = threadIdx.x;
  const int bh = blockIdx.x >> 3;
  const int xo = blockIdx.x & 7;

  const float2* __restrict__ kb = ksel + bh * 8192;
  for (int i = tid; i < 8192; i += 512) Kl[i] = kb[i];

  const int xr = tid & 63;
  const int yh = tid >> 6;           // 0..7
  const int x = xo * 64 + xr;
  const float2* __restrict__ qb = qsel + bh * 8192;
  float qr[16], qi[16], ar[16], ai[16];
  sfor<16>([&](auto E) {
    constexpr int e = decltype(E)::value;
    const float2 v = qb[e * 512 + x];
    qr[e] = v.x; qi[e] = v.y;
    ar[e] = 0.f; ai[e] = 0.f;
  });
  __syncthreads();

  const int y0 = yh * 64;
  for (int y = y0; y < y0 + 64; ++y) {
    float kr[16], ki[16];
    float sr = 0.f, si = 0.f;
    sfor<16>([&](auto E) {
      constexpr int e = decltype(E)::value;
      const float2 v = Kl[e * 512 + y];      // wave-uniform -> broadcast
      kr[e] = v.x; ki[e] = v.y;
      sr = fmaf(qr[e], v.x, fmaf(-qi[e], v.y, sr));
      si = fmaf(qr[e], v.y, fmaf( qi[e], v.x, si));
    });
    // complex tanh(sr + i si) = (sinh 2a + i sin 2b) / (cosh 2a + cos 2b)
    float a2 = 2.f * sr;
    a2 = fminf(fmaxf(a2, -30.f), 30.f);
    const float b2 = 2.f * si;
    const float ea = expf(a2);
    const float ei = 1.f / ea;
    const float sh = 0.5f * (ea - ei);
    const float chp = 0.5f * (ea + ei);
    float sb, cb;
    sincosf(b2, &sb, &cb);
    const float inv = 1.f / (chp + cb);
    const float tr = sh * inv;
    const float ti = sb * inv;
    sfor<16>([&](auto E) {
      constexpr int e = decltype(E)::value;
      ar[e] = fmaf(tr, kr[e], fmaf(-ti, ki[e], ar[e]));
      ai[e] = fmaf(tr, ki[e], fmaf( ti, kr[e], ai[e]));
    });
  }
  __syncthreads();
  float* __restrict__ red = (float*)Kl;   // K dead; 16384 floats available
  if (yh) {
    const int g = yh - 1;                 // 0..6
    sfor<16>([&](auto E) {
      constexpr int e = decltype(E)::value;
      red[(g * 32 + 2 * e) * 64 + xr] = ar[e];
      red[(g * 32 + 2 * e + 1) * 64 + xr] = ai[e];
    });
  }
  __syncthreads();
  if (!yh) {
    float2* __restrict__ ob = xqkv + bh * 8192;
    sfor<16>([&](auto E) {
      constexpr int e = decltype(E)::value;
      float sr2 = ar[e], si2 = ai[e];
      #pragma unroll
      for (int g = 0; g < 7; ++g) {
        sr2 += red[(g * 32 + 2 * e) * 64 + xr];
        si2 += red[(g * 32 + 2 * e + 1) * 64 + xr];
      }
      ob[e * 512 + x] = make_float2(sr2, si2);
    });
  }
}

// ---------------------------------------------------------------------------
// Kernel 3: w-multiply + analytic canonicalized inverse transform.
// out = (1/2^22) * sum_{k} w2(k2) cos(2pi k2 n2/64) * Re[F e^{i 2pi(k0n0+k1n1)/32}]
// grid 1024 = (b,h,o); block 256. Separable: A over k2, B over k1, C over k0.
// ---------------------------------------------------------------------------
#define SCALE_OUT (1.f / 4194304.f)

__global__ __launch_bounds__(256, 2)
void k3_inv(const float2* __restrict__ xqkv, const float* __restrict__ w_re,
            const float* __restrict__ w_im, float* __restrict__ out)
{
  __shared__ float2 Fs[512];
  __shared__ float cn[64];                   // cos(2*pi*t/64)
  __shared__ float Ur[4096], Ui[4096];       // [p=k0*8+k1][n2]
  __shared__ float Vr[2048], Vi[2048];       // [k0*4+n1loc][n2], 4-n1 chunks

  const int tid = threadIdx.x;
  const int bho = blockIdx.x;
  const int o = bho & 15;
  const int h = (bho >> 4) & 7;
  const int bh = bho >> 4;                   // b*8+h

  if (tid < 64) cn[tid] = cosf((float)tid * (PI_F / 32.f));

  float cc[17];
  sfor<17>([&](auto J) { constexpr int j = decltype(J)::value;
    cc[j] = cosf((float)j * (PI_F / 32.f)); });
  #define TCOSr(T) (fold_sgn(T) * cc[fold_idx(T)])
  #define TSINr(T) (fold_sgn(((T) + 48) & 63) * cc[fold_idx(((T) + 48) & 63)])

  // F[x] = sum_e xqkv[e,x] * w[e,o,x], scaled
  const float2* __restrict__ xb = xqkv + bh * 8192;
  const float* __restrict__ wrb = w_re + ((size_t)(h * 256 + o)) * 512;
  const float* __restrict__ wib = w_im + ((size_t)(h * 256 + o)) * 512;
  for (int x = tid; x < 512; x += 256) {
    float fr = 0.f, fi = 0.f;
    sfor<16>([&](auto E) {
      constexpr int e = decltype(E)::value;
      const float2 v = xb[e * 512 + x];
      const float wr = wrb[e * 8192 + x];
      const float wi = wib[e * 8192 + x];
      fr = fmaf(v.x, wr, fmaf(-v.y, wi, fr));
      fi = fmaf(v.x, wi, fmaf( v.y, wr, fi));
    });
    Fs[x] = make_float2(fr * SCALE_OUT, fi * SCALE_OUT);
  }
  __syncthreads();

  const int n2 = tid & 63;
  const int wv = tid >> 6;

  // stage A: U[p][n2] = sum_k2 w2(k2) cos(2pi k2 n2/64) F[p*8+k2]
  #pragma unroll
  for (int i = 0; i < 16; ++i) {
    const int p = wv * 16 + i;
    float ur = 0.f, ui = 0.f;
    sfor<8>([&](auto KC) {
      constexpr int k2 = decltype(KC)::value;
      const float2 f = Fs[p * 8 + k2];       // wave-uniform broadcast
      const float cv = cn[(k2 * n2) & 63];
      const float wgt = (k2 == 0) ? cv : 2.f * cv;
      ur = fmaf(wgt, f.x, ur);
      ui = fmaf(wgt, f.y, ui);
    });
    Ur[p * 64 + n2] = ur;
    Ui[p * 64 + n2] = ui;
  }
  __syncthreads();

  // per-thread U registers for its two k0 columns
  float u_r[2][8], u_i[2][8];
  sfor<2>([&](auto JC) {
    constexpr int j = decltype(JC)::value;
    sfor<8>([&](auto KC) {
      constexpr int k1 = decltype(KC)::value;
      const int p = (wv * 2 + j) * 8 + k1;
      u_r[j][k1] = Ur[p * 64 + n2];
      u_i[j][k1] = Ui[p * 64 + n2];
    });
  });

  float* __restrict__ ob = out + (size_t)bho * 65536;

  for (int chq = 0; chq < 8; ++chq) {        // 4 n1 values per chunk
    // stage B: V[k0][n1loc][n2] = sum_k1 U * e^{+i 2pi k1 n1/32}
    sfor<2>([&](auto JC) {
      constexpr int j = decltype(JC)::value;
      const int k0 = wv * 2 + j;
      sfor<4>([&](auto LC) {
        constexpr int l = decltype(LC)::value;
        const int n1 = chq * 4 + l;
        float vr = 0.f, vi = 0.f;
        sfor<8>([&](auto KC) {
          constexpr int k1 = decltype(KC)::value;
          const int t = (2 * k1 * n1) & 63;  // wave-uniform -> broadcast reads
          const float cv = cn[t];
          const float sv = cn[(t + 48) & 63];
          vr = fmaf(u_r[j][k1], cv, fmaf(-u_i[j][k1], sv, vr));
          vi = fmaf(u_r[j][k1], sv, fmaf( u_i[j][k1], cv, vi));
        });
        Vr[(k0 * 4 + l) * 64 + n2] = vr;
        Vi[(k0 * 4 + l) * 64 + n2] = vi;
      });
    });
    __syncthreads();
    // stage C: out[n0][n1][n2] = sum_k0 Vr cos - Vi sin   (literal twiddles)
    {
      const int l = wv;
      float vrr[8], vii[8];
      sfor<8>([&](auto KC) {
        constexpr int k0 = decltype(KC)::value;
        vrr[k0] = Vr[(k0 * 4 + l) * 64 + n2];
        vii[k0] = Vi[(k0 * 4 + l) * 64 + n2];
      });
      const int n1 = chq * 4 + l;
      float* __restrict__ op = ob + n1 * 64 + n2;
      sfor<32>([&](auto NC) {
        constexpr int n0 = decltype(NC)::value;
        float acc = vrr[0];
        sfor<7>([&](auto KC) {
          constexpr int k0 = decltype(KC)::value + 1;
          constexpr int t = (2 * k0 * n0) & 63;
          acc = fmaf(vrr[k0], TCOSr(t), fmaf(-vii[k0], TSINr(t), acc));
        });
        op[n0 * 2048] = acc;
      });
    }
    __syncthreads();
  }
}

// ---------------------------------------------------------------------------
extern "C" void kernel_launch(void* const* d_in, const int* in_sizes, int n_in,
                              void* d_out, int out_size, void* d_ws, size_t ws_size,
                              hipStream_t stream)
{
  (void)in_sizes; (void)n_in; (void)out_size; (void)ws_size;
  const float* q    = (const float*)d_in[0];
  const float* k    = (const float*)d_in[1];
  const float* w_re = (const float*)d_in[2];
  const float* w_im = (const float*)d_in[3];
  float* out = (float*)d_out;

  // workspace: qsel(4MB) | ksel(4MB) | xqkv(4MB), all [bh][e][x] float2
  float2* qsel = (float2*)d_ws;
  float2* ksel = qsel + 1024 * 512;
  float2* xqkv = ksel + 1024 * 512;

  hipLaunchKernelGGL(k1_fwd_dft, dim3(2048), dim3(512), 0, stream, q, k, qsel, ksel);
  hipLaunchKernelGGL(k2_attn,    dim3(512),  dim3(512), 0, stream, qsel, ksel, xqkv);
  hipLaunchKernelGGL(k3_inv,     dim3(1024), dim3(256), 0, stream, xqkv, w_re, w_im, out);
}